// Round 13
// baseline (782.872 us; speedup 1.0000x reference)
//
#include <hip/hip_runtime.h>
#include <hip/hip_fp16.h>
#include <math.h>

#define DIM 4096
#define RDIM 16
#define RIDGE 1e-5f
#define NPKP 144    // padded pair count (9 MFMA tiles of 16)
#define KCH 8       // K-chunks for MFMA buildA
#define KT 128      // k-tile staged in LDS per buildA inner iteration
#define NC 4        // columns owned per k_hub block

typedef __attribute__((ext_vector_type(8))) short bf16x8;
typedef __attribute__((ext_vector_type(4))) float f32x4;
typedef _Float16 hf2 __attribute__((ext_vector_type(2)));

#if defined(__has_builtin)
#if __has_builtin(__builtin_amdgcn_fdot2)
#define HAVE_FDOT2 1
#endif
#endif

__device__ __forceinline__ int pidx(int r, int s) { return r * (31 - r) / 2 + s; } // r<=s

__device__ __forceinline__ float alpha_of(float cl) {
    return cl * (1.f - erff(sqrtf(cl))) +
           0.5f * (erff(cl * 0.70710678118f) -
                   0.79788456080f * cl * expf(-0.5f * cl * cl));
}

__device__ __forceinline__ unsigned short bf16_rne(float p) {
    unsigned bits = __float_as_uint(p);
    return (unsigned short)((bits + 0x7FFFu + ((bits >> 16) & 1u)) >> 16);
}

// half-pair u32 -> bf16 0/1 mask pair u32 (nonzero-magnitude test per half)
__device__ __forceinline__ unsigned mask2_of(unsigned w) {
    return ((w & 0x00007FFFu) ? 0x00003F80u : 0u) |
           ((w & 0x7FFF0000u) ? 0x3F800000u : 0u);
}

// 16-elem dot of a fp16 row (8 packed u32 words) with fp16 beta (8 x hf2),
// fp32 accumulate. v_dot2_f32_f16 when available.
__device__ __forceinline__ float dot16(const unsigned* uw, const hf2* b2) {
    float d = 0.f;
#if HAVE_FDOT2
#pragma unroll
    for (int q = 0; q < 8; ++q) {
        union { unsigned u; hf2 h; } cv;
        cv.u = uw[q];
        d = __builtin_amdgcn_fdot2(cv.h, b2[q], d, false);
    }
#else
#pragma unroll
    for (int q = 0; q < 8; ++q) {
        union { unsigned u; hf2 h; } cv;
        cv.u = uw[q];
        d += (float)cv.h[0] * (float)b2[q][0] + (float)cv.h[1] * (float)b2[q][1];
    }
#endif
    return d;
}

// ------- transpose: X(fp32) -> Xh (fp16, row-major) + XhT (fp16, transposed)
// fused per-column and per-row observed counts.
__global__ void __launch_bounds__(256) k_transpose(const float* __restrict__ X,
                                                   __half* __restrict__ Xh,
                                                   __half* __restrict__ XhT,
                                                   float* __restrict__ cntc,
                                                   float* __restrict__ cntr) {
    __shared__ float tile[64][65];
    __shared__ float redc[4][64];
    __shared__ float redr[4][64];
    int bx = blockIdx.x, by = blockIdx.y;
    int lx = threadIdx.x & 63;
    int ly = threadIdx.x >> 6;
    float ccnt = 0.f;
#pragma unroll
    for (int i = 0; i < 16; ++i) {
        int r = ly + i * 4;
        float v = X[(size_t)(by * 64 + r) * DIM + bx * 64 + lx];
        tile[r][lx] = v;
        Xh[(size_t)(by * 64 + r) * DIM + bx * 64 + lx] = __float2half(v);
        ccnt += (v != 0.f) ? 1.f : 0.f;
    }
    redc[ly][lx] = ccnt;
    __syncthreads();
#pragma unroll
    for (int i = 0; i < 16; ++i) {
        int r = ly + i * 4;
        XhT[(size_t)(bx * 64 + r) * DIM + by * 64 + lx] = __float2half(tile[lx][r]);
    }
    float rcnt = 0.f;
#pragma unroll
    for (int j = 0; j < 16; ++j)
        rcnt += (tile[lx][ly * 16 + j] != 0.f) ? 1.f : 0.f;
    redr[ly][lx] = rcnt;
    __syncthreads();
    if (threadIdx.x < 64) {
        int c = threadIdx.x;
        atomicAdd(&cntc[bx * 64 + c],
                  redc[0][c] + redc[1][c] + redc[2][c] + redc[3][c]);
    } else if (threadIdx.x < 128) {
        int r = threadIdx.x - 64;
        atomicAdd(&cntr[by * 64 + r],
                  redr[0][r] + redr[1][r] + redr[2][r] + redr[3][r]);
    }
}

// ---------------- init copies ----------------------------------------------
__global__ void k_init_uc(const float* __restrict__ U, float* __restrict__ Uc,
                          __half* __restrict__ Uch) {
    int i = blockIdx.x * 256 + threadIdx.x;
    float4 v = ((const float4*)U)[i];
    ((float4*)Uc)[i] = v;
    __half2 h0 = __floats2half2_rn(v.x, v.y);
    __half2 h1 = __floats2half2_rn(v.z, v.w);
    *(__half2*)(Uch + (size_t)i * 4)     = h0;
    *(__half2*)(Uch + (size_t)i * 4 + 2) = h1;
}
__global__ void k_init_vt(const float* __restrict__ V, float* __restrict__ Vtb) {
    int n = blockIdx.x * 256 + threadIdx.x;
#pragma unroll
    for (int r = 0; r < RDIM; ++r) Vtb[(size_t)n * RDIM + r] = V[(size_t)r * DIM + n];
}

// ---------------- Pt[rs][m] = bf16(D[m][r] * D[m][s]), pidx order ----------
// Only used ONCE (layer-0 V step); later Pt builds fused into k_hub epilogue.
__global__ void __launch_bounds__(256) k_prep(const float* __restrict__ D,
                                              unsigned short* __restrict__ Pt) {
    int rs = blockIdx.y;
    int rr = 16, ss = 0;
#pragma unroll
    for (int r = 0; r < 16; ++r) {
        int base = r * (31 - r) / 2;
        if (rs >= base + r && rs <= base + 15) { rr = r; ss = rs - base; }
    }
    int m = blockIdx.x * 256 + threadIdx.x;
    float p = 0.f;
    if (rr < 16) p = D[(size_t)m * RDIM + rr] * D[(size_t)m * RDIM + ss];
    Pt[(size_t)rs * DIM + m] = bf16_rne(p);
}

// ---------------- MFMA buildA, KT=128, 16B staging loads -------------------
// grid 512: (bid&63) = c-block of 64, (bid>>6) = k-chunk (0..7, 512 k each).
__global__ void __launch_bounds__(256) k_buildA(const __half* __restrict__ XphT,
                                                const unsigned short* __restrict__ Pt,
                                                float* __restrict__ Apad) {
    __shared__ unsigned short wtile[64][KT + 8];
    __shared__ unsigned short ptile[144][KT + 8];
    const int tid = threadIdx.x;
    const int wave = tid >> 6;
    const int lane = tid & 63;
    const int n = lane & 15;
    const int quad = lane >> 4;
    const int c0 = (blockIdx.x & 63) * 64;
    const int kch = blockIdx.x >> 6;
    const int kbase0 = kch * (DIM / KCH);

    f32x4 acc[9];
#pragma unroll
    for (int t = 0; t < 9; ++t) acc[t] = (f32x4){0.f, 0.f, 0.f, 0.f};

    for (int kt = 0; kt < (DIM / KCH) / KT; ++kt) {   // 4 iterations
        const int kb = kbase0 + kt * KT;
        __syncthreads();
#pragma unroll
        for (int j = 0; j < 4; ++j) {
            int idx = j * 256 + tid;
            int r = idx >> 4;
            int ccol = (idx & 15) * 8;
            uint4 v = *(const uint4*)(XphT + (size_t)(c0 + r) * DIM + kb + ccol);
            uint4 mk;
            mk.x = mask2_of(v.x);
            mk.y = mask2_of(v.y);
            mk.z = mask2_of(v.z);
            mk.w = mask2_of(v.w);
            *(uint4*)&wtile[r][ccol] = mk;
        }
#pragma unroll
        for (int j = 0; j < 9; ++j) {
            int idx = j * 256 + tid;
            int pr = idx >> 4;
            int pc = (idx & 15) * 8;
            *(uint4*)&ptile[pr][pc] = *(const uint4*)(Pt + (size_t)pr * DIM + kb + pc);
        }
        __syncthreads();
#pragma unroll
        for (int inner = 0; inner < 4; ++inner) {
            bf16x8 bfrag = *(const bf16x8*)&wtile[wave * 16 + n][inner * 32 + quad * 8];
#pragma unroll
            for (int t = 0; t < 9; ++t) {
                bf16x8 afrag = *(const bf16x8*)&ptile[t * 16 + n][inner * 32 + quad * 8];
                acc[t] = __builtin_amdgcn_mfma_f32_16x16x32_bf16(afrag, bfrag, acc[t], 0, 0, 0);
            }
        }
    }
    const int c = c0 + wave * 16 + n;
    float* dst0 = Apad + ((size_t)kch * DIM + c) * NPKP + quad * 4;
#pragma unroll
    for (int t = 0; t < 9; ++t)
        *(float4*)(dst0 + t * 16) = (float4){acc[t].x, acc[t].y, acc[t].z, acc[t].w};
}

// =================== fused per-column hubreg solver ========================
// grid 1024 blocks x 256 thr. Block owns NC=4 columns (c0..c0+3).
// Pass A: threads partition rows, all 4 columns (verified round-8 math).
// Pass C: WAVE-PER-COLUMN — wave wv owns column wv, sweeps all 4096 rows,
// v[16] accumulator (no spill; round-12's merged v[64] spilled ~25 regs),
// wave-local reduce writes t_sh[wv] directly (no cross-wave stage).
__global__ void __launch_bounds__(256, 4)
k_hub(const __half* __restrict__ XsrcT, const __half* __restrict__ Dh,
      const float* __restrict__ Apad, const float* __restrict__ sigma,
      const float* __restrict__ cnt, const float* __restrict__ cvec,
      const float* __restrict__ lvec, const float* __restrict__ mvec,
      int layer, float* __restrict__ B, __half* __restrict__ Bh,
      unsigned short* __restrict__ Pt, int do_pt) {
    __shared__ __align__(16) __half Xcol[NC * DIM];   // 32 KB, [c][m] linear
    __shared__ float ainv_s[NC][16][16];              // 4 KB
    __shared__ float red_s[4][64];                    // 1 KB (pass A)
    __shared__ float t_sh[NC][16];
    __shared__ float beta_s[NC][16];
    __shared__ float sig_s[NC];
    __shared__ float Ared[NC * NPKP];                 // 2.25 KB (summed A rows)
    const int tid = threadIdx.x;
    const int wv = tid >> 6, ln = tid & 63;
    const int c0 = blockIdx.x * NC;

    // ---- stage: NC contiguous rows of XsrcT, fully coalesced uint4 copy ----
    {
        const uint4* src = (const uint4*)(XsrcT + (size_t)c0 * DIM);
        uint4* dst = (uint4*)Xcol;
#pragma unroll
        for (int q = 0; q < (NC * DIM) / (256 * 8); ++q)   // 8 iterations
            dst[q * 256 + tid] = src[q * 256 + tid];
    }
    if (tid >= 128 && tid < 128 + NC * 16) {
        int t2 = tid - 128;
        beta_s[t2 >> 4][t2 & 15] = B[(size_t)(c0 + (t2 >> 4)) * RDIM + (t2 & 15)];
    }
    // ---- cooperative A chunk-reduction: all 256 threads, coalesced --------
#pragma unroll
    for (int base = 0; base < NC * NPKP; base += 256) {
        int idx = base + tid;
        if (idx < NC * NPKP) {
            int cc = idx / NPKP;            // const divide (magic mul)
            int e  = idx - cc * NPKP;
            float s = 0.f;
#pragma unroll
            for (int ch = 0; ch < KCH; ++ch)
                s += Apad[((size_t)ch * DIM + c0 + cc) * NPKP + e];
            Ared[idx] = s;
        }
    }
    __syncthreads();
    // ---- invert NC SPD 16x16 (threads 0..63; 16-lane groups) ----
    if (tid < NC * 16) {
        int cc = tid >> 4;
        int j = tid & 15;
        float a[16], b[16];
#pragma unroll
        for (int s = 0; s < 16; ++s) {
            int r0 = j < s ? j : s;
            int s0_ = j < s ? s : j;
            a[s] = Ared[cc * NPKP + pidx(r0, s0_)];
            b[s] = 0.f;
        }
        a[j] += RIDGE;
        b[j] = 1.f;
#pragma unroll
        for (int k = 0; k < RDIM; ++k) {
            float pivA[16], pivB[16];
#pragma unroll
            for (int s = 0; s < 16; ++s) {
                pivA[s] = __shfl(a[s], k, 16);
                pivB[s] = __shfl(b[s], k, 16);
            }
            float pinv = 1.f / pivA[k];
            float f = a[k];
            if (j == k) {
#pragma unroll
                for (int s = 0; s < 16; ++s) { a[s] = pivA[s] * pinv; b[s] = pivB[s] * pinv; }
            } else {
#pragma unroll
                for (int s = 0; s < 16; ++s) {
                    a[s] -= f * pinv * pivA[s];
                    b[s] -= f * pinv * pivB[s];
                }
            }
        }
#pragma unroll
        for (int s = 0; s < 16; ++s) ainv_s[cc][j][s] = b[s];
    }
    __syncthreads();

    const float cl = cvec[layer], ll = lvec[layer], ml = mvec[layer];
    const float al = alpha_of(cl);
    const float s0inv = 1.f / sigma[0];

    for (int it = 0; it < 2; ++it) {
        // ================= pass A: psi^2 -> sig ===========================
        {
            float invs[NC];
#pragma unroll
            for (int c = 0; c < NC; ++c)
                invs[c] = (it == 0) ? s0inv : 1.f / sig_s[c];
            hf2 bb2[NC][8];
#pragma unroll
            for (int c = 0; c < NC; ++c)
#pragma unroll
                for (int q = 0; q < 8; ++q)
                    bb2[c][q] = hf2{(_Float16)beta_s[c][2 * q],
                                    (_Float16)beta_s[c][2 * q + 1]};
            float acc[NC];
#pragma unroll
            for (int c = 0; c < NC; ++c) acc[c] = 0.f;
#pragma unroll 4
            for (int k = 0; k < 16; ++k) {
                int m = tid + (k << 8);
                union { uint4 w[2]; unsigned u[8]; } uu;
                uu.w[0] = *(const uint4*)(Dh + (size_t)m * RDIM);
                uu.w[1] = *(const uint4*)(Dh + (size_t)m * RDIM + 8);
#pragma unroll
                for (int c = 0; c < NC; ++c) {
                    float xv = __half2float(Xcol[c * DIM + m]);
                    float dot = dot16(uu.u, bb2[c]);
                    float res = (xv != 0.f) ? (xv - dot) : 0.f;
                    float psi = fminf(fmaxf(res * invs[c], -cl), cl);
                    acc[c] = fmaf(psi, psi, acc[c]);
                }
            }
            // wave tree-reduce: 4 values -> lane (ln&3) holds wave total
            int h1 = (ln >> 1) & 1;
            float k0 = h1 ? acc[2] : acc[0], s0_ = h1 ? acc[0] : acc[2];
            float k1 = h1 ? acc[3] : acc[1], s1_ = h1 ? acc[1] : acc[3];
            float r0 = k0 + __shfl_xor(s0_, 2, 64);
            float r1 = k1 + __shfl_xor(s1_, 2, 64);
            int h0 = ln & 1;
            float kk = h0 ? r1 : r0, ss_ = h0 ? r0 : r1;
            float v = kk + __shfl_xor(ss_, 1, 64);
#pragma unroll
            for (int off = 4; off < 64; off <<= 1)
                v += __shfl_xor(v, off, 64);
            if (ln < NC) red_s[wv][ln] = v;
        }
        __syncthreads();
        if (tid < NC) {
            float sn = red_s[0][tid] + red_s[1][tid] + red_s[2][tid] + red_s[3][tid];
            sig_s[tid] = ll * sqrtf(sn) * rsqrtf(2.f * cnt[c0 + tid] * al);
        }
        __syncthreads();

        // ====== pass C: wave-per-column t accumulation (no spill) =========
        {
            const int cc = wv;              // wave wv owns column cc
            float sg = sig_s[cc];
            float isg = 1.f / sg;
            hf2 b2[8];
#pragma unroll
            for (int q = 0; q < 8; ++q)
                b2[q] = hf2{(_Float16)beta_s[cc][2 * q],
                            (_Float16)beta_s[cc][2 * q + 1]};
            float v[16];
#pragma unroll
            for (int s = 0; s < 16; ++s) v[s] = 0.f;
#pragma unroll 4
            for (int k = 0; k < 64; ++k) {
                int m = ln + (k << 6);
                union { uint4 w[2]; unsigned u[8]; _Float16 h[16]; } uu;
                uu.w[0] = *(const uint4*)(Dh + (size_t)m * RDIM);
                uu.w[1] = *(const uint4*)(Dh + (size_t)m * RDIM + 8);
                float xv = __half2float(Xcol[cc * DIM + m]);
                float dot = dot16(uu.u, b2);
                float res = (xv != 0.f) ? (xv - dot) : 0.f;
                float cf = fminf(fmaxf(res * isg, -cl), cl) * sg;
#pragma unroll
                for (int s = 0; s < 16; ++s)
                    v[s] = fmaf((float)uu.h[s], cf, v[s]);   // v_fma_mix
            }
            // reduce 16 values over 64 lanes: value-halving within 16-lane
            // groups (xor 8,4,2,1) -> lane holds value (ln&15); then fold
            // the four 16-lane subgroups (xor 16, 32). Value selects only,
            // no runtime array indexing (rule #20).
#pragma unroll
            for (int b = 3; b >= 0; --b) {
                const int half = 1 << b;
                int hi = (ln >> b) & 1;
#pragma unroll
                for (int j = 0; j < half; ++j) {
                    float lo_v = v[j], hi_v = v[j + half];
                    float keep = hi ? hi_v : lo_v;
                    float send = hi ? lo_v : hi_v;
                    v[j] = keep + __shfl_xor(send, half, 64);
                }
            }
            float tv = v[0];
            tv += __shfl_xor(tv, 16, 64);
            tv += __shfl_xor(tv, 32, 64);
            if (ln < 16) t_sh[cc][ln] = tv;   // wave-owned row, no cross-wave sum
        }
        __syncthreads();

        // ================= update: beta += mu * Ainv t =====================
        if (tid < 64) {
            int c = tid >> 4, j = tid & 15;
            float d = 0.f;
#pragma unroll
            for (int q = 0; q < 4; ++q) {
                float4 a4 = *(float4*)&ainv_s[c][j][q * 4];
                d += a4.x * t_sh[c][q * 4 + 0] + a4.y * t_sh[c][q * 4 + 1] +
                     a4.z * t_sh[c][q * 4 + 2] + a4.w * t_sh[c][q * 4 + 3];
            }
            beta_s[c][j] += ml * d;
        }
        __syncthreads();
    }

    // ================= epilogue ===========================================
    if (tid < NC * 16) {
        int c = tid >> 4, j = tid & 15;
        float bv = beta_s[c][j];
        B[(size_t)(c0 + c) * RDIM + j] = bv;
        Bh[(size_t)(c0 + c) * RDIM + j] = __float2half(bv);
    }
    if (do_pt && tid >= 112 && tid < 256) {
        int rs = tid - 112;
        int rr = 16, ss = 0;
#pragma unroll
        for (int r = 0; r < 16; ++r) {
            int base = r * (31 - r) / 2;
            if (rs >= base + r && rs <= base + 15) { rr = r; ss = rs - base; }
        }
#pragma unroll
        for (int c = 0; c < NC; ++c) {
            float p = (rr < 16) ? beta_s[c][rr] * beta_s[c][ss] : 0.f;
            Pt[(size_t)rs * DIM + c0 + c] = bf16_rne(p);
        }
    }
}

// ---------------- final out = Uc @ Vtb^T -----------------------------------
__global__ void __launch_bounds__(256) k_out(const float* __restrict__ Uc,
                                             const float* __restrict__ Vtb,
                                             float* __restrict__ out) {
    __shared__ float us[64 * RDIM];
    int j = blockIdx.x * 256 + threadIdx.x;
    int i0 = blockIdx.y * 64;
    ((float4*)us)[threadIdx.x] = ((const float4*)(Uc + (size_t)i0 * RDIM))[threadIdx.x];
    float beta[16];
#pragma unroll
    for (int q = 0; q < 4; ++q) {
        float4 t4 = ((const float4*)(Vtb + (size_t)j * RDIM))[q];
        beta[q * 4 + 0] = t4.x; beta[q * 4 + 1] = t4.y;
        beta[q * 4 + 2] = t4.z; beta[q * 4 + 3] = t4.w;
    }
    __syncthreads();
#pragma unroll 4
    for (int r = 0; r < 64; ++r) {
        float dot = 0.f;
#pragma unroll
        for (int q = 0; q < 4; ++q) {
            float4 u4 = *(const float4*)(us + r * RDIM + q * 4);
            dot += u4.x * beta[q * 4 + 0] + u4.y * beta[q * 4 + 1] +
                   u4.z * beta[q * 4 + 2] + u4.w * beta[q * 4 + 3];
        }
        out[(size_t)(i0 + r) * DIM + j] = dot;
    }
}

extern "C" void kernel_launch(void* const* d_in, const int* in_sizes, int n_in,
                              void* d_out, int out_size, void* d_ws, size_t ws_size,
                              hipStream_t stream) {
    const float* U = (const float*)d_in[0];
    const float* V = (const float*)d_in[1];
    const float* X = (const float*)d_in[2];
    const float* cvec = (const float*)d_in[3];
    const float* lvec = (const float*)d_in[4];
    const float* mvec = (const float*)d_in[5];
    const float* sigma = (const float*)d_in[6];
    float* out = (float*)d_out;

    float* ws = (float*)d_ws;
    float* Apad = ws;                                   // KCH*DIM*NPKP = 4.72M f
    float* cntc = Apad + (size_t)KCH * DIM * NPKP;      // DIM
    float* cntr = cntc + DIM;                           // DIM
    float* Uc   = cntr + DIM;                           // DIM*16
    float* Vtb  = Uc + (size_t)DIM * RDIM;              // DIM*16
    __half* Uch  = (__half*)(Vtb + (size_t)DIM * RDIM); // DIM*16 halves
    __half* Vtbh = Uch + (size_t)DIM * RDIM;            // DIM*16 halves
    unsigned short* Pt = (unsigned short*)(Vtbh + (size_t)DIM * RDIM); // 144*DIM u16
    // fp16 X copies live in d_out (scratch until k_out): exactly fills out_size.
    __half* Xh  = (__half*)out;
    __half* XhT = Xh + (size_t)DIM * DIM;

    hipMemsetAsync(cntc, 0, (size_t)2 * DIM * sizeof(float), stream);

    k_transpose<<<dim3(64, 64), 256, 0, stream>>>(X, Xh, XhT, cntc, cntr);
    k_init_uc<<<64, 256, 0, stream>>>(U, Uc, Uch);
    k_init_vt<<<16, 256, 0, stream>>>(V, Vtb);
    k_prep<<<dim3(16, NPKP), 256, 0, stream>>>(Uc, Pt);

    for (int layer = 0; layer < 3; ++layer) {
        int last = (layer == 2);
        // ---- V step: design Uc/Uch; solved entities = columns of X, which
        //      are contiguous rows of XhT (both buildA and hub read XhT) ----
        k_buildA<<<512, 256, 0, stream>>>(XhT, Pt, Apad);
        k_hub<<<1024, 256, 0, stream>>>(XhT, Uch, Apad, sigma, cntc,
                                        cvec, lvec, mvec, layer,
                                        Vtb, Vtbh, Pt, 1);
        // ---- U step: design Vtb/Vtbh; solved entities = rows of X ----
        k_buildA<<<512, 256, 0, stream>>>(Xh, Pt, Apad);
        k_hub<<<1024, 256, 0, stream>>>(Xh, Vtbh, Apad, sigma, cntr,
                                        cvec, lvec, mvec, layer,
                                        Uc, Uch, last ? nullptr : Pt, last ? 0 : 1);
    }
    k_out<<<dim3(16, 64), 256, 0, stream>>>(Uc, Vtb, out);
}

// Round 14
// 710.372 us; speedup vs baseline: 1.1021x; 1.1021x over previous
//
#include <hip/hip_runtime.h>
#include <hip/hip_fp16.h>
#include <math.h>

#define DIM 4096
#define RDIM 16
#define RIDGE 1e-5f
#define NPKP 144    // padded pair count (9 MFMA tiles of 16)
#define KCH 8       // K-chunks for MFMA buildA
#define KT 128      // k-tile staged in LDS per buildA inner iteration
#define NC 4        // columns owned per k_hub block

typedef __attribute__((ext_vector_type(8))) short bf16x8;
typedef __attribute__((ext_vector_type(4))) float f32x4;
typedef _Float16 hf2 __attribute__((ext_vector_type(2)));

#if defined(__has_builtin)
#if __has_builtin(__builtin_amdgcn_fdot2)
#define HAVE_FDOT2 1
#endif
#endif

__device__ __forceinline__ int pidx(int r, int s) { return r * (31 - r) / 2 + s; } // r<=s

__device__ __forceinline__ float alpha_of(float cl) {
    return cl * (1.f - erff(sqrtf(cl))) +
           0.5f * (erff(cl * 0.70710678118f) -
                   0.79788456080f * cl * expf(-0.5f * cl * cl));
}

__device__ __forceinline__ unsigned short bf16_rne(float p) {
    unsigned bits = __float_as_uint(p);
    return (unsigned short)((bits + 0x7FFFu + ((bits >> 16) & 1u)) >> 16);
}

// half-pair u32 -> bf16 0/1 mask pair u32 (nonzero-magnitude test per half)
__device__ __forceinline__ unsigned mask2_of(unsigned w) {
    return ((w & 0x00007FFFu) ? 0x00003F80u : 0u) |
           ((w & 0x7FFF0000u) ? 0x3F800000u : 0u);
}

// 16-elem dot of a fp16 row (8 packed u32 words) with fp16 beta (8 x hf2),
// fp32 accumulate. v_dot2_f32_f16 when available.
__device__ __forceinline__ float dot16(const unsigned* uw, const hf2* b2) {
    float d = 0.f;
#if HAVE_FDOT2
#pragma unroll
    for (int q = 0; q < 8; ++q) {
        union { unsigned u; hf2 h; } cv;
        cv.u = uw[q];
        d = __builtin_amdgcn_fdot2(cv.h, b2[q], d, false);
    }
#else
#pragma unroll
    for (int q = 0; q < 8; ++q) {
        union { unsigned u; hf2 h; } cv;
        cv.u = uw[q];
        d += (float)cv.h[0] * (float)b2[q][0] + (float)cv.h[1] * (float)b2[q][1];
    }
#endif
    return d;
}

// ------- transpose: X(fp32) -> Xh (fp16, row-major) + XhT (fp16, transposed)
// fused per-column and per-row observed counts.
__global__ void __launch_bounds__(256) k_transpose(const float* __restrict__ X,
                                                   __half* __restrict__ Xh,
                                                   __half* __restrict__ XhT,
                                                   float* __restrict__ cntc,
                                                   float* __restrict__ cntr) {
    __shared__ float tile[64][65];
    __shared__ float redc[4][64];
    __shared__ float redr[4][64];
    int bx = blockIdx.x, by = blockIdx.y;
    int lx = threadIdx.x & 63;
    int ly = threadIdx.x >> 6;
    float ccnt = 0.f;
#pragma unroll
    for (int i = 0; i < 16; ++i) {
        int r = ly + i * 4;
        float v = X[(size_t)(by * 64 + r) * DIM + bx * 64 + lx];
        tile[r][lx] = v;
        Xh[(size_t)(by * 64 + r) * DIM + bx * 64 + lx] = __float2half(v);
        ccnt += (v != 0.f) ? 1.f : 0.f;
    }
    redc[ly][lx] = ccnt;
    __syncthreads();
#pragma unroll
    for (int i = 0; i < 16; ++i) {
        int r = ly + i * 4;
        XhT[(size_t)(bx * 64 + r) * DIM + by * 64 + lx] = __float2half(tile[lx][r]);
    }
    float rcnt = 0.f;
#pragma unroll
    for (int j = 0; j < 16; ++j)
        rcnt += (tile[lx][ly * 16 + j] != 0.f) ? 1.f : 0.f;
    redr[ly][lx] = rcnt;
    __syncthreads();
    if (threadIdx.x < 64) {
        int c = threadIdx.x;
        atomicAdd(&cntc[bx * 64 + c],
                  redc[0][c] + redc[1][c] + redc[2][c] + redc[3][c]);
    } else if (threadIdx.x < 128) {
        int r = threadIdx.x - 64;
        atomicAdd(&cntr[by * 64 + r],
                  redr[0][r] + redr[1][r] + redr[2][r] + redr[3][r]);
    }
}

// ---------------- init copies ----------------------------------------------
__global__ void k_init_uc(const float* __restrict__ U, float* __restrict__ Uc,
                          __half* __restrict__ Uch) {
    int i = blockIdx.x * 256 + threadIdx.x;
    float4 v = ((const float4*)U)[i];
    ((float4*)Uc)[i] = v;
    __half2 h0 = __floats2half2_rn(v.x, v.y);
    __half2 h1 = __floats2half2_rn(v.z, v.w);
    *(__half2*)(Uch + (size_t)i * 4)     = h0;
    *(__half2*)(Uch + (size_t)i * 4 + 2) = h1;
}
__global__ void k_init_vt(const float* __restrict__ V, float* __restrict__ Vtb) {
    int n = blockIdx.x * 256 + threadIdx.x;
#pragma unroll
    for (int r = 0; r < RDIM; ++r) Vtb[(size_t)n * RDIM + r] = V[(size_t)r * DIM + n];
}

// ---------------- Pt[rs][m] = bf16(D[m][r] * D[m][s]), pidx order ----------
// Only used ONCE (layer-0 V step); later Pt builds fused into k_hub epilogue.
__global__ void __launch_bounds__(256) k_prep(const float* __restrict__ D,
                                              unsigned short* __restrict__ Pt) {
    int rs = blockIdx.y;
    int rr = 16, ss = 0;
#pragma unroll
    for (int r = 0; r < 16; ++r) {
        int base = r * (31 - r) / 2;
        if (rs >= base + r && rs <= base + 15) { rr = r; ss = rs - base; }
    }
    int m = blockIdx.x * 256 + threadIdx.x;
    float p = 0.f;
    if (rr < 16) p = D[(size_t)m * RDIM + rr] * D[(size_t)m * RDIM + ss];
    Pt[(size_t)rs * DIM + m] = bf16_rne(p);
}

// ---------------- MFMA buildA, KT=128, 16B staging loads -------------------
// grid 512: (bid&63) = c-block of 64, (bid>>6) = k-chunk (0..7, 512 k each).
__global__ void __launch_bounds__(256) k_buildA(const __half* __restrict__ XphT,
                                                const unsigned short* __restrict__ Pt,
                                                float* __restrict__ Apad) {
    __shared__ unsigned short wtile[64][KT + 8];
    __shared__ unsigned short ptile[144][KT + 8];
    const int tid = threadIdx.x;
    const int wave = tid >> 6;
    const int lane = tid & 63;
    const int n = lane & 15;
    const int quad = lane >> 4;
    const int c0 = (blockIdx.x & 63) * 64;
    const int kch = blockIdx.x >> 6;
    const int kbase0 = kch * (DIM / KCH);

    f32x4 acc[9];
#pragma unroll
    for (int t = 0; t < 9; ++t) acc[t] = (f32x4){0.f, 0.f, 0.f, 0.f};

    for (int kt = 0; kt < (DIM / KCH) / KT; ++kt) {   // 4 iterations
        const int kb = kbase0 + kt * KT;
        __syncthreads();
#pragma unroll
        for (int j = 0; j < 4; ++j) {
            int idx = j * 256 + tid;
            int r = idx >> 4;
            int ccol = (idx & 15) * 8;
            uint4 v = *(const uint4*)(XphT + (size_t)(c0 + r) * DIM + kb + ccol);
            uint4 mk;
            mk.x = mask2_of(v.x);
            mk.y = mask2_of(v.y);
            mk.z = mask2_of(v.z);
            mk.w = mask2_of(v.w);
            *(uint4*)&wtile[r][ccol] = mk;
        }
#pragma unroll
        for (int j = 0; j < 9; ++j) {
            int idx = j * 256 + tid;
            int pr = idx >> 4;
            int pc = (idx & 15) * 8;
            *(uint4*)&ptile[pr][pc] = *(const uint4*)(Pt + (size_t)pr * DIM + kb + pc);
        }
        __syncthreads();
#pragma unroll
        for (int inner = 0; inner < 4; ++inner) {
            bf16x8 bfrag = *(const bf16x8*)&wtile[wave * 16 + n][inner * 32 + quad * 8];
#pragma unroll
            for (int t = 0; t < 9; ++t) {
                bf16x8 afrag = *(const bf16x8*)&ptile[t * 16 + n][inner * 32 + quad * 8];
                acc[t] = __builtin_amdgcn_mfma_f32_16x16x32_bf16(afrag, bfrag, acc[t], 0, 0, 0);
            }
        }
    }
    const int c = c0 + wave * 16 + n;
    float* dst0 = Apad + ((size_t)kch * DIM + c) * NPKP + quad * 4;
#pragma unroll
    for (int t = 0; t < 9; ++t)
        *(float4*)(dst0 + t * 16) = (float4){acc[t].x, acc[t].y, acc[t].z, acc[t].w};
}

// =================== fused per-column hubreg solver ========================
// grid 1024 blocks x 256 thr. Block owns NC=4 columns (c0..c0+3).
// Round-12 dataflow (merged pass C: ONE k-loop, one Dh row load feeds all 4
// columns, v[64] accumulator). launch_bounds(256,3) raises the VGPR cap to
// ~170 so v[64] + b2[4][8] stay in registers (round 12 spilled at the
// (256,4)/128 cap; round 13's wave-per-column quadrupled Dh reads — both
// inferior).
__global__ void __launch_bounds__(256, 3)
k_hub(const __half* __restrict__ XsrcT, const __half* __restrict__ Dh,
      const float* __restrict__ Apad, const float* __restrict__ sigma,
      const float* __restrict__ cnt, const float* __restrict__ cvec,
      const float* __restrict__ lvec, const float* __restrict__ mvec,
      int layer, float* __restrict__ B, __half* __restrict__ Bh,
      unsigned short* __restrict__ Pt, int do_pt) {
    __shared__ __align__(16) __half Xcol[NC * DIM];   // 32 KB, [c][m] linear
    __shared__ float ainv_s[NC][16][16];              // 4 KB
    __shared__ float red_s[4][64];                    // 1 KB
    __shared__ float t_sh[NC][16];
    __shared__ float beta_s[NC][16];
    __shared__ float sig_s[NC];
    __shared__ float Ared[NC * NPKP];                 // 2.25 KB (summed A rows)
    const int tid = threadIdx.x;
    const int wv = tid >> 6, ln = tid & 63;
    const int c0 = blockIdx.x * NC;

    // ---- stage: NC contiguous rows of XsrcT, fully coalesced uint4 copy ----
    {
        const uint4* src = (const uint4*)(XsrcT + (size_t)c0 * DIM);
        uint4* dst = (uint4*)Xcol;
#pragma unroll
        for (int q = 0; q < (NC * DIM) / (256 * 8); ++q)   // 8 iterations
            dst[q * 256 + tid] = src[q * 256 + tid];
    }
    if (tid >= 128 && tid < 128 + NC * 16) {
        int t2 = tid - 128;
        beta_s[t2 >> 4][t2 & 15] = B[(size_t)(c0 + (t2 >> 4)) * RDIM + (t2 & 15)];
    }
    // ---- cooperative A chunk-reduction: all 256 threads, coalesced --------
#pragma unroll
    for (int base = 0; base < NC * NPKP; base += 256) {
        int idx = base + tid;
        if (idx < NC * NPKP) {
            int cc = idx / NPKP;            // const divide (magic mul)
            int e  = idx - cc * NPKP;
            float s = 0.f;
#pragma unroll
            for (int ch = 0; ch < KCH; ++ch)
                s += Apad[((size_t)ch * DIM + c0 + cc) * NPKP + e];
            Ared[idx] = s;
        }
    }
    __syncthreads();
    // ---- invert NC SPD 16x16 (threads 0..63; 16-lane groups) ----
    if (tid < NC * 16) {
        int cc = tid >> 4;
        int j = tid & 15;
        float a[16], b[16];
#pragma unroll
        for (int s = 0; s < 16; ++s) {
            int r0 = j < s ? j : s;
            int s0_ = j < s ? s : j;
            a[s] = Ared[cc * NPKP + pidx(r0, s0_)];
            b[s] = 0.f;
        }
        a[j] += RIDGE;
        b[j] = 1.f;
#pragma unroll
        for (int k = 0; k < RDIM; ++k) {
            float pivA[16], pivB[16];
#pragma unroll
            for (int s = 0; s < 16; ++s) {
                pivA[s] = __shfl(a[s], k, 16);
                pivB[s] = __shfl(b[s], k, 16);
            }
            float pinv = 1.f / pivA[k];
            float f = a[k];
            if (j == k) {
#pragma unroll
                for (int s = 0; s < 16; ++s) { a[s] = pivA[s] * pinv; b[s] = pivB[s] * pinv; }
            } else {
#pragma unroll
                for (int s = 0; s < 16; ++s) {
                    a[s] -= f * pinv * pivA[s];
                    b[s] -= f * pinv * pivB[s];
                }
            }
        }
#pragma unroll
        for (int s = 0; s < 16; ++s) ainv_s[cc][j][s] = b[s];
    }
    __syncthreads();

    const float cl = cvec[layer], ll = lvec[layer], ml = mvec[layer];
    const float al = alpha_of(cl);
    const float s0inv = 1.f / sigma[0];

    for (int it = 0; it < 2; ++it) {
        // ================= pass A: psi^2 -> sig ===========================
        {
            float invs[NC];
#pragma unroll
            for (int c = 0; c < NC; ++c)
                invs[c] = (it == 0) ? s0inv : 1.f / sig_s[c];
            hf2 bb2[NC][8];
#pragma unroll
            for (int c = 0; c < NC; ++c)
#pragma unroll
                for (int q = 0; q < 8; ++q)
                    bb2[c][q] = hf2{(_Float16)beta_s[c][2 * q],
                                    (_Float16)beta_s[c][2 * q + 1]};
            float acc[NC];
#pragma unroll
            for (int c = 0; c < NC; ++c) acc[c] = 0.f;
#pragma unroll 4
            for (int k = 0; k < 16; ++k) {
                int m = tid + (k << 8);
                union { uint4 w[2]; unsigned u[8]; } uu;
                uu.w[0] = *(const uint4*)(Dh + (size_t)m * RDIM);
                uu.w[1] = *(const uint4*)(Dh + (size_t)m * RDIM + 8);
#pragma unroll
                for (int c = 0; c < NC; ++c) {
                    float xv = __half2float(Xcol[c * DIM + m]);
                    float dot = dot16(uu.u, bb2[c]);
                    float res = (xv != 0.f) ? (xv - dot) : 0.f;
                    float psi = fminf(fmaxf(res * invs[c], -cl), cl);
                    acc[c] = fmaf(psi, psi, acc[c]);
                }
            }
            // wave tree-reduce: 4 values -> lane (ln&3) holds wave total
            int h1 = (ln >> 1) & 1;
            float k0 = h1 ? acc[2] : acc[0], s0_ = h1 ? acc[0] : acc[2];
            float k1 = h1 ? acc[3] : acc[1], s1_ = h1 ? acc[1] : acc[3];
            float r0 = k0 + __shfl_xor(s0_, 2, 64);
            float r1 = k1 + __shfl_xor(s1_, 2, 64);
            int h0 = ln & 1;
            float kk = h0 ? r1 : r0, ss_ = h0 ? r0 : r1;
            float v = kk + __shfl_xor(ss_, 1, 64);
#pragma unroll
            for (int off = 4; off < 64; off <<= 1)
                v += __shfl_xor(v, off, 64);
            if (ln < NC) red_s[wv][ln] = v;
        }
        __syncthreads();
        if (tid < NC) {
            float sn = red_s[0][tid] + red_s[1][tid] + red_s[2][tid] + red_s[3][tid];
            sig_s[tid] = ll * sqrtf(sn) * rsqrtf(2.f * cnt[c0 + tid] * al);
        }
        __syncthreads();

        // ====== pass C: t accumulation, all 4 columns in ONE k-loop =======
        {
            float sg[4], isg[4];
            hf2 b2[4][8];
#pragma unroll
            for (int i = 0; i < 4; ++i) {
                sg[i] = sig_s[i];
                isg[i] = 1.f / sg[i];
#pragma unroll
                for (int q = 0; q < 8; ++q)
                    b2[i][q] = hf2{(_Float16)beta_s[i][2 * q],
                                   (_Float16)beta_s[i][2 * q + 1]};
            }
            float v[64];   // tac flattened: idx = c*16+s
#pragma unroll
            for (int j = 0; j < 64; ++j) v[j] = 0.f;
#pragma unroll 2
            for (int k = 0; k < 16; ++k) {
                int m = tid + (k << 8);
                union { uint4 w[2]; unsigned u[8]; _Float16 h[16]; } uu;
                uu.w[0] = *(const uint4*)(Dh + (size_t)m * RDIM);
                uu.w[1] = *(const uint4*)(Dh + (size_t)m * RDIM + 8);
                float cf0, cf1, cf2, cf3;
                {
                    float xv = __half2float(Xcol[0 * DIM + m]);
                    float dot = dot16(uu.u, b2[0]);
                    float res = (xv != 0.f) ? (xv - dot) : 0.f;
                    cf0 = fminf(fmaxf(res * isg[0], -cl), cl) * sg[0];
                }
                {
                    float xv = __half2float(Xcol[1 * DIM + m]);
                    float dot = dot16(uu.u, b2[1]);
                    float res = (xv != 0.f) ? (xv - dot) : 0.f;
                    cf1 = fminf(fmaxf(res * isg[1], -cl), cl) * sg[1];
                }
                {
                    float xv = __half2float(Xcol[2 * DIM + m]);
                    float dot = dot16(uu.u, b2[2]);
                    float res = (xv != 0.f) ? (xv - dot) : 0.f;
                    cf2 = fminf(fmaxf(res * isg[2], -cl), cl) * sg[2];
                }
                {
                    float xv = __half2float(Xcol[3 * DIM + m]);
                    float dot = dot16(uu.u, b2[3]);
                    float res = (xv != 0.f) ? (xv - dot) : 0.f;
                    cf3 = fminf(fmaxf(res * isg[3], -cl), cl) * sg[3];
                }
#pragma unroll
                for (int s = 0; s < 16; ++s) {
                    float us = (float)uu.h[s];          // v_fma_mix folds cvt
                    v[s]      = fmaf(us, cf0, v[s]);
                    v[16 + s] = fmaf(us, cf1, v[16 + s]);
                    v[32 + s] = fmaf(us, cf2, v[32 + s]);
                    v[48 + s] = fmaf(us, cf3, v[48 + s]);
                }
            }
            // wave tree-reduce 64 values -> lane ln holds total of index ln;
            // value selects only, no runtime array indexing (rule #20).
#pragma unroll
            for (int b = 5; b >= 0; --b) {
                const int half = 1 << b;
                int hi = (ln >> b) & 1;
#pragma unroll
                for (int j = 0; j < half; ++j) {
                    float lo_v = v[j], hi_v = v[j + half];
                    float keep = hi ? hi_v : lo_v;
                    float send = hi ? lo_v : hi_v;
                    v[j] = keep + __shfl_xor(send, half, 64);
                }
            }
            red_s[wv][ln] = v[0];
        }
        __syncthreads();

        // ================= update: beta += mu * Ainv t =====================
        if (tid < 64)
            t_sh[tid >> 4][tid & 15] = red_s[0][tid] + red_s[1][tid] +
                                       red_s[2][tid] + red_s[3][tid];
        __syncthreads();
        if (tid < 64) {
            int c = tid >> 4, j = tid & 15;
            float d = 0.f;
#pragma unroll
            for (int q = 0; q < 4; ++q) {
                float4 a4 = *(float4*)&ainv_s[c][j][q * 4];
                d += a4.x * t_sh[c][q * 4 + 0] + a4.y * t_sh[c][q * 4 + 1] +
                     a4.z * t_sh[c][q * 4 + 2] + a4.w * t_sh[c][q * 4 + 3];
            }
            beta_s[c][j] += ml * d;
        }
        __syncthreads();
    }

    // ================= epilogue ===========================================
    if (tid < NC * 16) {
        int c = tid >> 4, j = tid & 15;
        float bv = beta_s[c][j];
        B[(size_t)(c0 + c) * RDIM + j] = bv;
        Bh[(size_t)(c0 + c) * RDIM + j] = __float2half(bv);
    }
    if (do_pt && tid >= 112 && tid < 256) {
        int rs = tid - 112;
        int rr = 16, ss = 0;
#pragma unroll
        for (int r = 0; r < 16; ++r) {
            int base = r * (31 - r) / 2;
            if (rs >= base + r && rs <= base + 15) { rr = r; ss = rs - base; }
        }
#pragma unroll
        for (int c = 0; c < NC; ++c) {
            float p = (rr < 16) ? beta_s[c][rr] * beta_s[c][ss] : 0.f;
            Pt[(size_t)rs * DIM + c0 + c] = bf16_rne(p);
        }
    }
}

// ---------------- final out = Uc @ Vtb^T -----------------------------------
__global__ void __launch_bounds__(256) k_out(const float* __restrict__ Uc,
                                             const float* __restrict__ Vtb,
                                             float* __restrict__ out) {
    __shared__ float us[64 * RDIM];
    int j = blockIdx.x * 256 + threadIdx.x;
    int i0 = blockIdx.y * 64;
    ((float4*)us)[threadIdx.x] = ((const float4*)(Uc + (size_t)i0 * RDIM))[threadIdx.x];
    float beta[16];
#pragma unroll
    for (int q = 0; q < 4; ++q) {
        float4 t4 = ((const float4*)(Vtb + (size_t)j * RDIM))[q];
        beta[q * 4 + 0] = t4.x; beta[q * 4 + 1] = t4.y;
        beta[q * 4 + 2] = t4.z; beta[q * 4 + 3] = t4.w;
    }
    __syncthreads();
#pragma unroll 4
    for (int r = 0; r < 64; ++r) {
        float dot = 0.f;
#pragma unroll
        for (int q = 0; q < 4; ++q) {
            float4 u4 = *(const float4*)(us + r * RDIM + q * 4);
            dot += u4.x * beta[q * 4 + 0] + u4.y * beta[q * 4 + 1] +
                   u4.z * beta[q * 4 + 2] + u4.w * beta[q * 4 + 3];
        }
        out[(size_t)(i0 + r) * DIM + j] = dot;
    }
}

extern "C" void kernel_launch(void* const* d_in, const int* in_sizes, int n_in,
                              void* d_out, int out_size, void* d_ws, size_t ws_size,
                              hipStream_t stream) {
    const float* U = (const float*)d_in[0];
    const float* V = (const float*)d_in[1];
    const float* X = (const float*)d_in[2];
    const float* cvec = (const float*)d_in[3];
    const float* lvec = (const float*)d_in[4];
    const float* mvec = (const float*)d_in[5];
    const float* sigma = (const float*)d_in[6];
    float* out = (float*)d_out;

    float* ws = (float*)d_ws;
    float* Apad = ws;                                   // KCH*DIM*NPKP = 4.72M f
    float* cntc = Apad + (size_t)KCH * DIM * NPKP;      // DIM
    float* cntr = cntc + DIM;                           // DIM
    float* Uc   = cntr + DIM;                           // DIM*16
    float* Vtb  = Uc + (size_t)DIM * RDIM;              // DIM*16
    __half* Uch  = (__half*)(Vtb + (size_t)DIM * RDIM); // DIM*16 halves
    __half* Vtbh = Uch + (size_t)DIM * RDIM;            // DIM*16 halves
    unsigned short* Pt = (unsigned short*)(Vtbh + (size_t)DIM * RDIM); // 144*DIM u16
    // fp16 X copies live in d_out (scratch until k_out): exactly fills out_size.
    __half* Xh  = (__half*)out;
    __half* XhT = Xh + (size_t)DIM * DIM;

    hipMemsetAsync(cntc, 0, (size_t)2 * DIM * sizeof(float), stream);

    k_transpose<<<dim3(64, 64), 256, 0, stream>>>(X, Xh, XhT, cntc, cntr);
    k_init_uc<<<64, 256, 0, stream>>>(U, Uc, Uch);
    k_init_vt<<<16, 256, 0, stream>>>(V, Vtb);
    k_prep<<<dim3(16, NPKP), 256, 0, stream>>>(Uc, Pt);

    for (int layer = 0; layer < 3; ++layer) {
        int last = (layer == 2);
        // ---- V step: design Uc/Uch; solved entities = columns of X, which
        //      are contiguous rows of XhT (both buildA and hub read XhT) ----
        k_buildA<<<512, 256, 0, stream>>>(XhT, Pt, Apad);
        k_hub<<<1024, 256, 0, stream>>>(XhT, Uch, Apad, sigma, cntc,
                                        cvec, lvec, mvec, layer,
                                        Vtb, Vtbh, Pt, 1);
        // ---- U step: design Vtb/Vtbh; solved entities = rows of X ----
        k_buildA<<<512, 256, 0, stream>>>(Xh, Pt, Apad);
        k_hub<<<1024, 256, 0, stream>>>(Xh, Vtbh, Apad, sigma, cntr,
                                        cvec, lvec, mvec, layer,
                                        Uc, Uch, last ? nullptr : Pt, last ? 0 : 1);
    }
    k_out<<<dim3(16, 64), 256, 0, stream>>>(Uc, Vtb, out);
}